// Round 2
// baseline (811.728 us; speedup 1.0000x reference)
//
#include <hip/hip_runtime.h>
#include <math.h>

#define BB 8
#define LL 8192
#define DD 64
#define HH 128
#define NN 64
#define NLAYER 3
#define NCHUNK 32
#define LCHUNK 256   // LL / NCHUNK

// workspace sizes in floats
#define SZ_H   ((size_t)BB*LL*HH)            // 8388608
#define SZ_SL  ((size_t)BB*HH*NCHUNK*NN*2)   // 4194304
#define SZ_P   ((size_t)HH*NN*2)             // 16384
#define SZ_WG4 ((size_t)NLAYER*32*256*4)     // 98304
#define SZ_WO4 ((size_t)32*64*4)             // 8192

// ---------------- weight transposes (float4-friendly layouts) ----------------
__global__ __launch_bounds__(256) void kW1(const float* __restrict__ Wglu,
                                           float4* __restrict__ wg4) {
  int tid = blockIdx.x*256 + threadIdx.x;        // < 3*32*256 = 24576
  int l   = tid >> 13;
  int rem = tid & 8191;
  int h4  = rem >> 8;
  int g   = rem & 255;
  const float* src = Wglu + ((size_t)(l*256 + g))*HH + h4*4;
  wg4[tid] = make_float4(src[0], src[1], src[2], src[3]);
}

__global__ __launch_bounds__(256) void kW2(const float* __restrict__ Wout,
                                           float4* __restrict__ wo4) {
  int tid = blockIdx.x*256 + threadIdx.x;        // < 2048
  int h4 = tid >> 6, d = tid & 63;
  wo4[tid] = make_float4(Wout[(h4*4+0)*DD + d], Wout[(h4*4+1)*DD + d],
                         Wout[(h4*4+2)*DD + d], Wout[(h4*4+3)*DD + d]);
}

// ---------------- input GEMM: h = x @ W_in + b_in ----------------
__global__ __launch_bounds__(256) void kIn(const float* __restrict__ x,
      const float* __restrict__ Win, const float* __restrict__ bin,
      float* __restrict__ hout) {
  __shared__ float xs[16][DD];
  size_t row0 = (size_t)blockIdx.x * 16;
  int t = threadIdx.x;
  #pragma unroll
  for (int k = 0; k < 4; k++) {
    int idx = t + k*256;
    int r = idx >> 6, cc = idx & 63;
    xs[r][cc] = x[(row0 + r)*DD + cc];
  }
  __syncthreads();
  int ccol = t & 127;
  int rg   = t >> 7;
  float acc[8];
  #pragma unroll
  for (int r = 0; r < 8; r++) acc[r] = bin[ccol];
  for (int k = 0; k < DD; k++) {
    float wv = Win[k*HH + ccol];
    #pragma unroll
    for (int r = 0; r < 8; r++) acc[r] = fmaf(wv, xs[rg*8 + r][k], acc[r]);
  }
  #pragma unroll
  for (int r = 0; r < 8; r++) hout[(row0 + rg*8 + r)*HH + ccol] = acc[r];
}

// ---------------- per-layer SSM parameter precompute ----------------
__global__ __launch_bounds__(256) void kP(const float* __restrict__ logdt,
   const float* __restrict__ logA, const float* __restrict__ Aim,
   const float* __restrict__ Cre, const float* __restrict__ Cim, int layer,
   float* __restrict__ wb, float* __restrict__ cb, float* __restrict__ wl) {
  int tid = blockIdx.x*256 + threadIdx.x;        // < HH*NN = 8192
  int n = tid & 63, h = tid >> 6;
  float dt = expf(logdt[layer*HH + h]);
  int idx = (layer*HH + h)*NN + n;
  float ar = -expf(logA[idx]);
  float ai = Aim[idx];
  float dr = dt*ar, di = dt*ai;
  float er = expf(dr);
  float wr_ = er*cosf(di), wi_ = er*sinf(di);     // w = exp(dt*A)
  float mr = wr_ - 1.f, mi = wi_;                 // expm1(dtA)
  float inv = 1.f/(ar*ar + ai*ai);
  float tr = (mr*ar + mi*ai)*inv;                 // expm1(dtA)/A
  float ti = (mi*ar - mr*ai)*inv;
  float c0 = Cre[idx], c1 = Cim[idx];
  cb[2*tid]   = c0*tr - c1*ti;                    // C_eff
  cb[2*tid+1] = c0*ti + c1*tr;
  wb[2*tid]   = wr_;
  wb[2*tid+1] = wi_;
  float pr = wr_, pi = wi_;                       // w^LCHUNK via 8 squarings
  for (int k = 0; k < 8; k++) { float qr = pr*pr - pi*pi; float qi = 2.f*pr*pi; pr = qr; pi = qi; }
  wl[2*tid] = pr; wl[2*tid+1] = pi;
}

// ---------------- kA: chunk-local end states (zero init) ----------------
// wave = 64 lanes: lane = g*8+j, h = hg*8+g, lane owns states n = j*8..j*8+7
__global__ __launch_bounds__(256) void kA(const float* __restrict__ hin,
        const float* __restrict__ wbuf, float* __restrict__ Sloc) {
  int wid  = blockIdx.x*4 + (threadIdx.x >> 6);
  int lane = threadIdx.x & 63;
  int c  = wid & (NCHUNK-1);
  int hg = (wid >> 5) & 15;
  int b  = wid >> 9;
  int g = lane >> 3, j = lane & 7;
  int h = hg*8 + g;
  int n0 = j*8;
  float wr[8], wi[8], sr[8], si[8];
  const float* wp = wbuf + ((size_t)h*NN + n0)*2;
  #pragma unroll
  for (int q = 0; q < 8; q++) { wr[q] = wp[2*q]; wi[q] = wp[2*q+1]; sr[q] = 0.f; si[q] = 0.f; }
  const float* up = hin + (size_t)b*LL*HH + h;
  int l0 = c*LCHUNK;
  for (int lb = 0; lb < LCHUNK; lb += 8) {
    float uv[8];
    #pragma unroll
    for (int q = 0; q < 8; q++) uv[q] = up[(size_t)(l0 + lb + q)*HH];
    #pragma unroll
    for (int q = 0; q < 8; q++) {
      float u = uv[q];
      #pragma unroll
      for (int st = 0; st < 8; st++) {
        float nr = fmaf(wr[st], sr[st], fmaf(-wi[st], si[st], u));
        float ni = fmaf(wi[st], sr[st], wr[st]*si[st]);
        sr[st] = nr; si[st] = ni;
      }
    }
  }
  float* Sp = Sloc + ((((size_t)b*HH + h)*NCHUNK + c)*NN + n0)*2;
  #pragma unroll
  for (int q = 0; q < 8; q++) { Sp[2*q] = sr[q]; Sp[2*q+1] = si[q]; }
}

// ---------------- kB: cross-chunk scan, in-place S_local -> s_init ----------------
__global__ __launch_bounds__(256) void kB(float* __restrict__ Sloc,
                                          const float* __restrict__ wl) {
  int tid = blockIdx.x*256 + threadIdx.x;        // < BB*HH*NN = 65536
  int n = tid & 63;
  int h = (tid >> 6) & 127;
  int b = tid >> 13;
  float wlr = wl[((size_t)h*NN + n)*2], wli = wl[((size_t)h*NN + n)*2 + 1];
  float cr = 0.f, ci = 0.f;
  float* base = Sloc + (((size_t)b*HH + h)*NCHUNK)*NN*2 + (size_t)n*2;
  for (int c = 0; c < NCHUNK; c++) {
    float* p = base + (size_t)c*NN*2;
    float tr_ = p[0], ti_ = p[1];
    p[0] = cr; p[1] = ci;
    float nr = fmaf(wlr, cr, fmaf(-wli, ci, tr_));
    float ni = fmaf(wli, cr, fmaf(wlr, ci, ti_));
    cr = nr; ci = ni;
  }
}

// ---------------- kC: full recurrence from s_init, y written to (B,L,H) ----------------
__global__ __launch_bounds__(256) void kC(const float* __restrict__ hin,
        const float* __restrict__ wbuf, const float* __restrict__ cbuf,
        const float* __restrict__ Sini, float* __restrict__ y) {
  int wid  = blockIdx.x*4 + (threadIdx.x >> 6);
  int lane = threadIdx.x & 63;
  int c  = wid & (NCHUNK-1);
  int hg = (wid >> 5) & 15;
  int b  = wid >> 9;
  int g = lane >> 3, j = lane & 7;
  int h = hg*8 + g;
  int n0 = j*8;
  float wr[8], wi[8], cre[8], cim[8], sr[8], si[8];
  {
    const float* wp = wbuf + ((size_t)h*NN + n0)*2;
    const float* cp = cbuf + ((size_t)h*NN + n0)*2;
    const float* sp = Sini + ((((size_t)b*HH + h)*NCHUNK + c)*NN + n0)*2;
    #pragma unroll
    for (int q = 0; q < 8; q++) {
      wr[q] = wp[2*q]; wi[q] = wp[2*q+1];
      cre[q] = cp[2*q]; cim[q] = cp[2*q+1];
      sr[q] = sp[2*q]; si[q] = sp[2*q+1];
    }
  }
  const float* up = hin + (size_t)b*LL*HH + h;
  float* yp = y + (size_t)b*LL*HH;
  int l0 = c*LCHUNK;
  for (int lb = 0; lb < LCHUNK; lb += 8) {
    float uv[8];
    #pragma unroll
    for (int q = 0; q < 8; q++) uv[q] = up[(size_t)(l0 + lb + q)*HH];
    float ystore = 0.f;
    #pragma unroll
    for (int q = 0; q < 8; q++) {
      float u = uv[q];
      #pragma unroll
      for (int st = 0; st < 8; st++) {
        float nr = fmaf(wr[st], sr[st], fmaf(-wi[st], si[st], u));
        float ni = fmaf(wi[st], sr[st], wr[st]*si[st]);
        sr[st] = nr; si[st] = ni;
      }
      float y0 = 0.f, y1 = 0.f;
      #pragma unroll
      for (int st = 0; st < 8; st += 2) {
        y0 = fmaf(cre[st],   sr[st],   y0); y0 = fmaf(-cim[st],   si[st],   y0);
        y1 = fmaf(cre[st+1], sr[st+1], y1); y1 = fmaf(-cim[st+1], si[st+1], y1);
      }
      float yv = y0 + y1;
      yv += __shfl_xor(yv, 1);
      yv += __shfl_xor(yv, 2);
      yv += __shfl_xor(yv, 4);
      if (j == q) ystore = 2.f*yv;
    }
    yp[(size_t)(l0 + lb + j)*HH + h] = ystore;   // lane(g,j) -> (l0+lb+j, h)
  }
}

// ---------------- kD: skip + gelu + GLU + residual + rmsnorm ----------------
// NOTE: y may alias hout (reads of y complete in stage 1; writes only in stage 5;
// blocks own disjoint row ranges).
__global__ __launch_bounds__(256) void kD(const float* __restrict__ y,
     const float* __restrict__ hin, const float* __restrict__ dskip,
     const float4* __restrict__ wg4, const float* __restrict__ bglu,
     float* __restrict__ hout) {
  __shared__ float yy[16][HH];      // gelu'd ssm output, later reused for glu+res
  __shared__ float zb[16][2*HH];
  __shared__ float rnorm[16];
  size_t row0 = (size_t)blockIdx.x * 16;
  int t = threadIdx.x;
  // stage 1: y + u*D_skip, gelu(tanh approx)
  #pragma unroll
  for (int k = 0; k < 8; k++) {
    int idx = t + k*256;
    int r = idx >> 7, m = idx & 127;
    float u = hin[(row0 + r)*HH + m];
    float v = y[(row0 + r)*HH + m] + u*dskip[m];
    float arg = 0.7978845608028654f*(v + 0.044715f*v*v*v);
    arg = fminf(fmaxf(arg, -15.f), 15.f);
    float e = __expf(2.f*arg);
    float th = (e - 1.f)/(e + 1.f);
    yy[r][m] = 0.5f*v*(1.f + th);
  }
  __syncthreads();
  // stage 2: GLU matmul z[r][g], g = t
  float acc[16];
  #pragma unroll
  for (int r = 0; r < 16; r++) acc[r] = bglu[t];
  for (int h4 = 0; h4 < 32; h4++) {
    float4 wv = wg4[h4*256 + t];
    #pragma unroll
    for (int r = 0; r < 16; r++) {
      const float4 y4 = *reinterpret_cast<const float4*>(&yy[r][h4*4]);
      acc[r] = fmaf(wv.x, y4.x, fmaf(wv.y, y4.y, fmaf(wv.z, y4.z, fmaf(wv.w, y4.w, acc[r]))));
    }
  }
  #pragma unroll
  for (int r = 0; r < 16; r++) zb[r][t] = acc[r];
  __syncthreads();
  // stage 3: a*sigmoid(gate) + residual -> reuse yy
  #pragma unroll
  for (int k = 0; k < 8; k++) {
    int idx = t + k*256;
    int r = idx >> 7, m = idx & 127;
    float a  = zb[r][m];
    float gt = zb[r][m + 128];
    float sg = 1.f/(1.f + __expf(-gt));
    yy[r][m] = fmaf(a, sg, hin[(row0 + r)*HH + m]);
  }
  __syncthreads();
  // stage 4: row 2-norms
  #pragma unroll
  for (int half = 0; half < 2; half++) {
    int r = (t >> 5) + half*8;
    int l32 = t & 31;
    float s = 0.f;
    #pragma unroll
    for (int m = 0; m < 4; m++) { float v = yy[r][l32 + m*32]; s = fmaf(v, v, s); }
    s += __shfl_xor(s, 1); s += __shfl_xor(s, 2); s += __shfl_xor(s, 4);
    s += __shfl_xor(s, 8); s += __shfl_xor(s, 16);
    if (l32 == 0) rnorm[r] = s;
  }
  __syncthreads();
  // stage 5: normalize + write
  #pragma unroll
  for (int k = 0; k < 8; k++) {
    int idx = t + k*256;
    int r = idx >> 7, m = idx & 127;
    float nr = sqrtf(rnorm[r]);
    float scale = 11.313708498984761f / fmaxf(nr, 1e-12f);
    hout[(row0 + r)*HH + m] = yy[r][m]*scale;
  }
}

// ---------------- kE: out = h @ W_out + b_out ----------------
__global__ __launch_bounds__(256) void kE(const float* __restrict__ hin,
      const float4* __restrict__ wo4, const float* __restrict__ bout,
      float* __restrict__ out) {
  __shared__ float hs[16][HH];
  size_t row0 = (size_t)blockIdx.x * 16;
  int t = threadIdx.x;
  #pragma unroll
  for (int k = 0; k < 8; k++) {
    int idx = t + k*256;
    int r = idx >> 7, m = idx & 127;
    hs[r][m] = hin[(row0 + r)*HH + m];
  }
  __syncthreads();
  int d = t & 63, rg = t >> 6;
  float acc[4];
  #pragma unroll
  for (int r = 0; r < 4; r++) acc[r] = bout[d];
  for (int h4 = 0; h4 < 32; h4++) {
    float4 wv = wo4[h4*64 + d];
    #pragma unroll
    for (int r = 0; r < 4; r++) {
      const float4 y4 = *reinterpret_cast<const float4*>(&hs[rg*4 + r][h4*4]);
      acc[r] = fmaf(wv.x, y4.x, fmaf(wv.y, y4.y, fmaf(wv.z, y4.z, fmaf(wv.w, y4.w, acc[r]))));
    }
  }
  #pragma unroll
  for (int r = 0; r < 4; r++) out[(row0 + rg*4 + r)*DD + d] = acc[r];
}

extern "C" void kernel_launch(void* const* d_in, const int* in_sizes, int n_in,
                              void* d_out, int out_size, void* d_ws, size_t ws_size,
                              hipStream_t stream) {
  const float* x     = (const float*)d_in[0];
  const float* Win   = (const float*)d_in[1];
  const float* bin   = (const float*)d_in[2];
  const float* logdt = (const float*)d_in[3];
  const float* logA  = (const float*)d_in[4];
  const float* Aim   = (const float*)d_in[5];
  const float* Cre   = (const float*)d_in[6];
  const float* Cim   = (const float*)d_in[7];
  const float* Dsk   = (const float*)d_in[8];
  const float* Wglu  = (const float*)d_in[9];
  const float* bglu  = (const float*)d_in[10];
  const float* Wout  = (const float*)d_in[11];
  const float* bout  = (const float*)d_in[12];
  float* out = (float*)d_out;

  float* ws  = (float*)d_ws;
  float* hA  = ws;
  float* hB  = hA + SZ_H;
  float* Sl  = hB + SZ_H;
  float* wb  = Sl + SZ_SL;
  float* cb  = wb + SZ_P;
  float* wl  = cb + SZ_P;
  float* wg4 = wl + SZ_P;
  float* wo4 = wg4 + SZ_WG4;
  // total floats: 2*SZ_H + SZ_SL + 3*SZ_P + SZ_WG4 + SZ_WO4 ≈ 21.1M (≈84.5 MB)

  hipLaunchKernelGGL(kW1, dim3(96),   dim3(256), 0, stream, Wglu, (float4*)wg4);
  hipLaunchKernelGGL(kW2, dim3(8),    dim3(256), 0, stream, Wout, (float4*)wo4);
  hipLaunchKernelGGL(kIn, dim3(4096), dim3(256), 0, stream, x, Win, bin, hA);

  float* hc = hA;
  float* hn = hB;
  for (int layer = 0; layer < NLAYER; ++layer) {
    hipLaunchKernelGGL(kP, dim3(32),   dim3(256), 0, stream,
                       logdt, logA, Aim, Cre, Cim, layer, wb, cb, wl);
    hipLaunchKernelGGL(kA, dim3(1024), dim3(256), 0, stream, hc, wb, Sl);
    hipLaunchKernelGGL(kB, dim3(256),  dim3(256), 0, stream, Sl, wl);
    // y goes into hn; kD reads it and overwrites hn in-place (safe, see note)
    hipLaunchKernelGGL(kC, dim3(1024), dim3(256), 0, stream, hc, wb, cb, Sl, hn);
    hipLaunchKernelGGL(kD, dim3(4096), dim3(256), 0, stream, hn, hc, Dsk + layer*HH,
                       (const float4*)(wg4 + (size_t)layer*32*256*4),
                       bglu + layer*2*HH, hn);
    float* tmp = hc; hc = hn; hn = tmp;
  }
  hipLaunchKernelGGL(kE, dim3(4096), dim3(256), 0, stream, hc, (const float4*)wo4, bout, out);
}